// Round 3
// baseline (70.516 us; speedup 1.0000x reference)
//
#include <hip/hip_runtime.h>
#include <math.h>

// Geometry fixed by reference: B=4, C=3, D=H=W=64.
#define VOXB 262144              // 64^3
#define NVOX 1048576             // 4 * VOXB
#define NACC 14
#define PITCH 65                 // LDS pitch: bank=(lane+j)%32 -> 2-way = free

// ---------------------------------------------------------------------------
// Squared distance (as float) from position i to nearest set bit of 64b mask.
// Empty mask -> 1000^2 = 1e6 (acts as +inf: never <= (r+1)^2 <= 4096,
// never beats a real candidate <= 2*63^2, clamped to 65535 on store and
// provably unused in the degenerate cases).
// ---------------------------------------------------------------------------
__device__ __forceinline__ float n2side(unsigned long long m, int i) {
    unsigned long long right = m >> i;
    unsigned long long left  = m << (63 - i);
    int dr = right ? __builtin_ctzll(right) : 1000;
    int dl = left  ? __builtin_clzll(left)  : 1000;
    int d  = dr < dl ? dr : dl;
    return (float)(d * d);
}

// ---------------------------------------------------------------------------
// Kernel A: per (b,d) plane. W-pass = one ballot per row (bit masks, 512B LDS).
// H-pass = radius spiral straight off the masks (VALU only), 8 rows per wave
// interleaved for ILP, uniform early exit. Output packed ushort2 (pos|neg<<16).
// Also zeroes the completion counter used by kernel B's fused final reduce.
// ---------------------------------------------------------------------------
__global__ __launch_bounds__(512) void edt_wh(const int* __restrict__ targets,
                                              unsigned int* __restrict__ d2wh,
                                              int* __restrict__ counter) {
    __shared__ unsigned long long Msk[64];
    if (blockIdx.x == 0 && threadIdx.x == 0) *counter = 0;
    int pb   = blockIdx.x * 4096;      // (b*64+d)*4096
    int wv   = threadIdx.x >> 6;
    int lane = threadIdx.x & 63;       // = w
    int hbase = wv * 8;

#pragma unroll
    for (int rt = 0; rt < 8; ++rt) {
        int h = hbase + rt;
        int tv = targets[pb + h * 64 + lane];
        unsigned long long m = __ballot(tv == 1);
        if (lane == 0) Msk[h] = m;
    }
    __syncthreads();

    float mp[8], mn[8];
#pragma unroll
    for (int rt = 0; rt < 8; ++rt) {
        unsigned long long m = Msk[hbase + rt];
        mp[rt] = n2side(m, lane);
        mn[rt] = n2side(~m, lane);
    }
    for (int r = 1; r < 64; ++r) {
        float rr = (float)(r * r);
        unsigned long long ml[8], mr[8];
#pragma unroll
        for (int rt = 0; rt < 8; ++rt) {
            int h = hbase + rt;
            int jl = h - r; jl = jl < 0 ? 0 : jl;
            int jr = h + r; jr = jr > 63 ? 63 : jr;
            ml[rt] = Msk[jl]; mr[rt] = Msk[jr];
        }
        bool ok = true;
        float thr = (float)((r + 1) * (r + 1));
#pragma unroll
        for (int rt = 0; rt < 8; ++rt) {
            mp[rt] = fminf(mp[rt], fminf(n2side(ml[rt], lane), n2side(mr[rt], lane)) + rr);
            mn[rt] = fminf(mn[rt], fminf(n2side(~ml[rt], lane), n2side(~mr[rt], lane)) + rr);
            ok = ok && (mp[rt] <= thr) && (mn[rt] <= thr);
        }
        if (__all(ok)) break;          // remaining candidates >= (r+1)^2
    }
#pragma unroll
    for (int rt = 0; rt < 8; ++rt) {
        unsigned int p = (unsigned int)fminf(mp[rt], 65535.0f);
        unsigned int n = (unsigned int)fminf(mn[rt], 65535.0f);
        d2wh[pb + (hbase + rt) * 64 + lane] = p | (n << 16);
    }
}

// ---------------------------------------------------------------------------
// Per-voxel pointwise math + accumulation.
// ---------------------------------------------------------------------------
__device__ __forceinline__ void vox_accum(float l0, float l1, float l2,
                                          int t, int s, float sd, float* acc) {
    float m  = fmaxf(l0, fmaxf(l1, l2));
    float e0 = __expf(l0 - m), e1 = __expf(l1 - m), e2 = __expf(l2 - m);
    float sum = e0 + e1 + e2;
    float inv = 1.0f / sum;
    float p0 = e0 * inv, p1 = e1 * inv, p2 = e2 * inv;
    float logs = __logf(sum);
    float pt, lpt, alpha;
    if (t == 0)      { pt = p0; lpt = l0 - m - logs; alpha = 0.3f; }
    else if (t == 1) { pt = p1; lpt = l1 - m - logs; alpha = 3.0f; }
    else             { pt = p2; lpt = l2 - m - logs; alpha = 0.3f; }
    float om = 1.0f - pt;
    acc[0] += alpha * om * om * lpt;
    acc[1] += (t == 0) ? p0 : 0.f;
    acc[2] += (t == 1) ? p1 : 0.f;
    acc[3] += (t == 2) ? p2 : 0.f;
    acc[4] += p0; acc[5] += p1; acc[6] += p2;
    acc[7] += (t == 0) ? 1.f : 0.f;
    acc[8] += (t == 1) ? 1.f : 0.f;
    acc[9] += (t == 2) ? 1.f : 0.f;
    float fs = (float)s;
    acc[10] += p1 * fs;
    acc[11] += fs;
    acc[12] += p1;
    acc[13] += p1 * sd;
}

// ---------------------------------------------------------------------------
// Kernel B: per (b,h) slab [d][w]. Transposed-LDS D-pass spiral (8 rows/wave
// interleaved for ILP, packed ushort2 values), fused pointwise + block
// reduction, and last-block final loss assembly (threadfence reduction).
// ---------------------------------------------------------------------------
__global__ __launch_bounds__(512) void edt_d_reduce(
        const float* __restrict__ logits, const int* __restrict__ targets,
        const int* __restrict__ skel, const unsigned int* __restrict__ d2wh,
        float* __restrict__ partials, int* __restrict__ counter,
        float* __restrict__ out) {
    __shared__ unsigned int T[64 * PITCH];   // T[w][d], packed pos|neg<<16
    __shared__ float red[8][NACC];
    __shared__ float sb[NACC][4];
    __shared__ int isLast;
    int b = blockIdx.x >> 6, h = blockIdx.x & 63;
    int vb = b * VOXB + h * 64;
    int t = threadIdx.x;

    // Load slab, transposing into LDS (coalesced uint4 global reads).
#pragma unroll
    for (int k = 0; k < 2; ++k) {
        int f  = k * 512 + t;          // 0..1023 uint4 groups
        int d  = f >> 4;
        int w0 = (f & 15) * 4;
        uint4 q = *reinterpret_cast<const uint4*>(d2wh + vb + d * 4096 + w0);
        T[(w0 + 0) * PITCH + d] = q.x;
        T[(w0 + 1) * PITCH + d] = q.y;
        T[(w0 + 2) * PITCH + d] = q.z;
        T[(w0 + 3) * PITCH + d] = q.w;
    }
    __syncthreads();

    int wv = t >> 6, lane = t & 63;    // lane = w
    int dbase = wv * 8;

    // Prefetch pointwise inputs (in flight during the spiral).
    int   tv[8], sv[8];
    float l0[8], l1[8], l2[8];
#pragma unroll
    for (int rt = 0; rt < 8; ++rt) {
        int d = dbase + rt;
        int voff = vb + d * 4096 + lane;
        tv[rt] = targets[voff];
        sv[rt] = skel[voff];
        size_t lb = (size_t)b * (3 * VOXB) + d * 4096 + h * 64 + lane;
        l0[rt] = logits[lb];
        l1[rt] = logits[lb + VOXB];
        l2[rt] = logits[lb + 2 * VOXB];
    }

    // D-axis spiral, 8 rows interleaved.
    float mp[8], mn[8];
#pragma unroll
    for (int rt = 0; rt < 8; ++rt) {
        unsigned int v = T[lane * PITCH + dbase + rt];
        mp[rt] = (float)(v & 0xffffu);
        mn[rt] = (float)(v >> 16);
    }
    for (int r = 1; r < 64; ++r) {
        float rr = (float)(r * r);
        unsigned int vl[8], vr[8];
#pragma unroll
        for (int rt = 0; rt < 8; ++rt) {
            int d = dbase + rt;
            int jl = d - r; jl = jl < 0 ? 0 : jl;
            int jr = d + r; jr = jr > 63 ? 63 : jr;
            vl[rt] = T[lane * PITCH + jl];
            vr[rt] = T[lane * PITCH + jr];
        }
        bool ok = true;
        float thr = (float)((r + 1) * (r + 1));
#pragma unroll
        for (int rt = 0; rt < 8; ++rt) {
            mp[rt] = fminf(mp[rt], fminf((float)(vl[rt] & 0xffffu), (float)(vr[rt] & 0xffffu)) + rr);
            mn[rt] = fminf(mn[rt], fminf((float)(vl[rt] >> 16), (float)(vr[rt] >> 16)) + rr);
            ok = ok && (mp[rt] <= thr) && (mn[rt] <= thr);
        }
        if (__all(ok)) break;
    }

    // Pointwise + per-thread accumulation.
    float acc[NACC];
#pragma unroll
    for (int k = 0; k < NACC; ++k) acc[k] = 0.f;
#pragma unroll
    for (int rt = 0; rt < 8; ++rt) {
        float sd = sqrtf(mp[rt]) - sqrtf(mn[rt]);
        vox_accum(l0[rt], l1[rt], l2[rt], tv[rt], sv[rt], sd, acc);
    }

    // Wave reduce -> LDS -> block partials.
#pragma unroll
    for (int k = 0; k < NACC; ++k) {
        float v = acc[k];
#pragma unroll
        for (int off = 32; off; off >>= 1) v += __shfl_down(v, off, 64);
        if (lane == 0) red[wv][k] = v;
    }
    __syncthreads();
    if (t < NACC) {
        float v = 0.f;
#pragma unroll
        for (int q = 0; q < 8; ++q) v += red[q][t];
        partials[t * 256 + blockIdx.x] = v;
    }

    // Last-block final reduction (threadfence-reduction pattern).
    __threadfence();
    __syncthreads();
    if (t == 0) {
        int prev = __hip_atomic_fetch_add(counter, 1, __ATOMIC_ACQ_REL,
                                          __HIP_MEMORY_SCOPE_AGENT);
        isLast = (prev == 255);
    }
    __syncthreads();
    if (isLast) {
        __threadfence();
        if (t < 256) {
            int w = t >> 6, ln = t & 63;
#pragma unroll
            for (int k = 0; k < NACC; ++k) {
                float v = partials[k * 256 + w * 64 + ln];
#pragma unroll
                for (int off = 32; off; off >>= 1) v += __shfl_down(v, off, 64);
                if (ln == 0) sb[k][w] = v;
            }
        }
        __syncthreads();
        if (t == 0) {
            double S[NACC];
#pragma unroll
            for (int k = 0; k < NACC; ++k)
                S[k] = (double)sb[k][0] + sb[k][1] + sb[k][2] + sb[k][3];
            const double W[3] = {0.3, 3.0, 0.3};
            double focal = -S[0] / (double)NVOX;
            double dice = 0.0;
            for (int c = 0; c < 3; ++c)
                dice += W[c] * (1.0 - (2.0 * S[1 + c] + 1.0) /
                                      (S[4 + c] + S[7 + c] + 1.0));
            double lfd = focal + dice / 3.6;
            double lsk = 1.0 - (S[10] + 1.0) / (S[11] + 1.0);
            double lb = 0.0;
            for (int bb = 0; bb < 4; ++bb) {
                double gs = sb[8][bb];
                double ps = sb[12][bb];
                double tm = sb[13][bb];
                double per;
                if (gs == 0.0)               per = ps / (double)VOXB;
                else if (gs == (double)VOXB) per = 1.0 - ps / (double)VOXB;
                else                         per = tm / (double)VOXB;
                lb += per;
            }
            lb *= 0.25;
            double total = 0.3 * lfd + 0.3 * lsk + 0.2 * lb;
            out[0] = (float)total;
            out[1] = (float)lfd;
            out[2] = (float)lsk;
            out[3] = (float)lb;
        }
    }
}

// ---------------------------------------------------------------------------
extern "C" void kernel_launch(void* const* d_in, const int* in_sizes, int n_in,
                              void* d_out, int out_size, void* d_ws, size_t ws_size,
                              hipStream_t stream) {
    const float* logits  = (const float*)d_in[0];
    const int*   targets = (const int*)d_in[1];
    const int*   skel    = (const int*)d_in[2];
    unsigned int* d2wh   = (unsigned int*)d_ws;            // NVOX uints (4 MB)
    float* partials      = (float*)(d2wh + NVOX);          // NACC*256 floats
    int*   counter       = (int*)(partials + NACC * 256);
    float* out = (float*)d_out;

    edt_wh<<<256, 512, 0, stream>>>(targets, d2wh, counter);
    edt_d_reduce<<<256, 512, 0, stream>>>(logits, targets, skel, d2wh,
                                          partials, counter, out);
}

// Round 4
// 29.711 us; speedup vs baseline: 2.3734x; 2.3734x over previous
//
#include <hip/hip_runtime.h>
#include <math.h>

// Geometry fixed by reference: B=4, C=3, D=H=W=64.
#define VOXB 262144              // 64^3
#define NVOX 1048576             // 4 * VOXB
#define NACC 14
#define PITCH 65                 // LDS pitch: bank=(lane+j)%32 -> 2-way = free
#define NBLK 512                 // grid for A and B (2 blocks per plane/slab)

// ---------------------------------------------------------------------------
// Squared distance (float) from position i to nearest set bit of 64b mask.
// Empty mask -> 1e6, clamped to 65535 on pack; a clamped value never beats a
// genuine candidate (max genuine value after H-pass is 2*63^2 = 7938, after
// D-pass 11907), and volumes where no genuine candidate exists take the
// gsum==0 / gsum==nvox branch in the final assembly, so clamping is exact.
// ---------------------------------------------------------------------------
__device__ __forceinline__ float n2side(unsigned long long m, int i) {
    unsigned long long right = m >> i;
    unsigned long long left  = m << (63 - i);
    int dr = right ? __builtin_ctzll(right) : 1000;
    int dl = left  ? __builtin_clzll(left)  : 1000;
    int d  = dr < dl ? dr : dl;
    return (float)(d * d);
}

// ---------------------------------------------------------------------------
// Kernel A: 2 blocks per (b,d) plane. Phase 1: W-pass via ballot bit-scan for
// all 64 rows, packed (pos|neg<<16) into transposed LDS T[w][h]. Phase 2:
// H-axis radius spiral with uniform early exit, 4 rows per wave (this block's
// half of the plane). Output packed ushort2.
// ---------------------------------------------------------------------------
__global__ __launch_bounds__(512) void edt_wh(const int* __restrict__ targets,
                                              unsigned int* __restrict__ d2wh) {
    __shared__ unsigned int T[64 * PITCH];   // T[w][h]
    int plane = blockIdx.x >> 1;             // b*64 + d
    int half  = blockIdx.x & 1;
    int pb    = plane * 4096;
    int wv    = threadIdx.x >> 6;
    int lane  = threadIdx.x & 63;            // = w

#pragma unroll
    for (int rt = 0; rt < 8; ++rt) {
        int h = wv * 8 + rt;
        int tv = targets[pb + h * 64 + lane];
        unsigned long long m = __ballot(tv == 1);
        unsigned int p = (unsigned int)fminf(n2side(m, lane), 65535.f);
        unsigned int n = (unsigned int)fminf(n2side(~m, lane), 65535.f);
        T[lane * PITCH + h] = p | (n << 16);
    }
    __syncthreads();

    int hbase = half * 32 + wv * 4;
    float mp[4], mn[4];
#pragma unroll
    for (int rt = 0; rt < 4; ++rt) {
        unsigned int v = T[lane * PITCH + hbase + rt];
        mp[rt] = (float)(v & 0xffffu);
        mn[rt] = (float)(v >> 16);
    }
    for (int r = 1; r < 64; ++r) {
        float rr = (float)(r * r);
        unsigned int vl[4], vr[4];
#pragma unroll
        for (int rt = 0; rt < 4; ++rt) {
            int h = hbase + rt;
            int jl = h - r; jl = jl < 0 ? 0 : jl;
            int jr = h + r; jr = jr > 63 ? 63 : jr;
            vl[rt] = T[lane * PITCH + jl];
            vr[rt] = T[lane * PITCH + jr];
        }
        bool ok = true;
        float thr = (float)((r + 1) * (r + 1));
#pragma unroll
        for (int rt = 0; rt < 4; ++rt) {
            mp[rt] = fminf(mp[rt], fminf((float)(vl[rt] & 0xffffu), (float)(vr[rt] & 0xffffu)) + rr);
            mn[rt] = fminf(mn[rt], fminf((float)(vl[rt] >> 16), (float)(vr[rt] >> 16)) + rr);
            ok = ok && (mp[rt] <= thr) && (mn[rt] <= thr);
        }
        if (__all(ok)) break;                // remaining candidates >= (r+1)^2
    }
#pragma unroll
    for (int rt = 0; rt < 4; ++rt) {
        unsigned int p = (unsigned int)fminf(mp[rt], 65535.0f);
        unsigned int n = (unsigned int)fminf(mn[rt], 65535.0f);
        d2wh[pb + (hbase + rt) * 64 + lane] = p | (n << 16);
    }
}

// ---------------------------------------------------------------------------
// Per-voxel pointwise math + accumulation.
// ---------------------------------------------------------------------------
__device__ __forceinline__ void vox_accum(float l0, float l1, float l2,
                                          int t, int s, float sd, float* acc) {
    float m  = fmaxf(l0, fmaxf(l1, l2));
    float e0 = __expf(l0 - m), e1 = __expf(l1 - m), e2 = __expf(l2 - m);
    float sum = e0 + e1 + e2;
    float inv = 1.0f / sum;
    float p0 = e0 * inv, p1 = e1 * inv, p2 = e2 * inv;
    float logs = __logf(sum);
    float pt, lpt, alpha;
    if (t == 0)      { pt = p0; lpt = l0 - m - logs; alpha = 0.3f; }
    else if (t == 1) { pt = p1; lpt = l1 - m - logs; alpha = 3.0f; }
    else             { pt = p2; lpt = l2 - m - logs; alpha = 0.3f; }
    float om = 1.0f - pt;
    acc[0] += alpha * om * om * lpt;
    acc[1] += (t == 0) ? p0 : 0.f;
    acc[2] += (t == 1) ? p1 : 0.f;
    acc[3] += (t == 2) ? p2 : 0.f;
    acc[4] += p0; acc[5] += p1; acc[6] += p2;
    acc[7] += (t == 0) ? 1.f : 0.f;
    acc[8] += (t == 1) ? 1.f : 0.f;
    acc[9] += (t == 2) ? 1.f : 0.f;
    float fs = (float)s;
    acc[10] += p1 * fs;
    acc[11] += fs;
    acc[12] += p1;
    acc[13] += p1 * sd;
}

// ---------------------------------------------------------------------------
// Kernel B: 2 blocks per (b,h) slab [d][w]. Full slab transposed into LDS
// (packed), D-axis spiral for 4 rows/wave, fused pointwise + block partials.
// No fences, no atomics — final reduction is a separate tiny kernel.
// ---------------------------------------------------------------------------
__global__ __launch_bounds__(512) void edt_d_reduce(
        const float* __restrict__ logits, const int* __restrict__ targets,
        const int* __restrict__ skel, const unsigned int* __restrict__ d2wh,
        float* __restrict__ partials) {
    __shared__ unsigned int T[64 * PITCH];   // T[w][d], packed pos|neg<<16
    __shared__ float red[8][NACC];
    int slab = blockIdx.x >> 1;              // b*64 + h
    int half = blockIdx.x & 1;
    int b = slab >> 6, h = slab & 63;
    int vb = b * VOXB + h * 64;
    int t = threadIdx.x;

    // Load full slab, transposing into LDS (coalesced uint4 global reads).
#pragma unroll
    for (int k = 0; k < 2; ++k) {
        int f  = k * 512 + t;                // 0..1023 uint4 groups
        int d  = f >> 4;
        int w0 = (f & 15) * 4;
        uint4 q = *reinterpret_cast<const uint4*>(d2wh + vb + d * 4096 + w0);
        T[(w0 + 0) * PITCH + d] = q.x;
        T[(w0 + 1) * PITCH + d] = q.y;
        T[(w0 + 2) * PITCH + d] = q.z;
        T[(w0 + 3) * PITCH + d] = q.w;
    }
    __syncthreads();

    int wv = t >> 6, lane = t & 63;          // lane = w
    int dbase = half * 32 + wv * 4;

    // Prefetch pointwise inputs (in flight during the spiral).
    int   tv[4], sv[4];
    float l0[4], l1[4], l2[4];
#pragma unroll
    for (int rt = 0; rt < 4; ++rt) {
        int d = dbase + rt;
        int voff = vb + d * 4096 + lane;
        tv[rt] = targets[voff];
        sv[rt] = skel[voff];
        size_t lb = (size_t)b * (3 * VOXB) + d * 4096 + h * 64 + lane;
        l0[rt] = logits[lb];
        l1[rt] = logits[lb + VOXB];
        l2[rt] = logits[lb + 2 * VOXB];
    }

    // D-axis spiral, 4 rows interleaved.
    float mp[4], mn[4];
#pragma unroll
    for (int rt = 0; rt < 4; ++rt) {
        unsigned int v = T[lane * PITCH + dbase + rt];
        mp[rt] = (float)(v & 0xffffu);
        mn[rt] = (float)(v >> 16);
    }
    for (int r = 1; r < 64; ++r) {
        float rr = (float)(r * r);
        unsigned int vl[4], vr[4];
#pragma unroll
        for (int rt = 0; rt < 4; ++rt) {
            int d = dbase + rt;
            int jl = d - r; jl = jl < 0 ? 0 : jl;
            int jr = d + r; jr = jr > 63 ? 63 : jr;
            vl[rt] = T[lane * PITCH + jl];
            vr[rt] = T[lane * PITCH + jr];
        }
        bool ok = true;
        float thr = (float)((r + 1) * (r + 1));
#pragma unroll
        for (int rt = 0; rt < 4; ++rt) {
            mp[rt] = fminf(mp[rt], fminf((float)(vl[rt] & 0xffffu), (float)(vr[rt] & 0xffffu)) + rr);
            mn[rt] = fminf(mn[rt], fminf((float)(vl[rt] >> 16), (float)(vr[rt] >> 16)) + rr);
            ok = ok && (mp[rt] <= thr) && (mn[rt] <= thr);
        }
        if (__all(ok)) break;
    }

    // Pointwise + per-thread accumulation.
    float acc[NACC];
#pragma unroll
    for (int k = 0; k < NACC; ++k) acc[k] = 0.f;
#pragma unroll
    for (int rt = 0; rt < 4; ++rt) {
        float sd = sqrtf(mp[rt]) - sqrtf(mn[rt]);
        vox_accum(l0[rt], l1[rt], l2[rt], tv[rt], sv[rt], sd, acc);
    }

    // Wave reduce -> LDS -> block partials.
#pragma unroll
    for (int k = 0; k < NACC; ++k) {
        float v = acc[k];
#pragma unroll
        for (int off = 32; off; off >>= 1) v += __shfl_down(v, off, 64);
        if (lane == 0) red[wv][k] = v;
    }
    __syncthreads();
    if (t < NACC) {
        float v = 0.f;
#pragma unroll
        for (int q = 0; q < 8; ++q) v += red[q][t];
        partials[t * NBLK + blockIdx.x] = v;
    }
}

// ---------------------------------------------------------------------------
// Kernel C: final reduction (1 block, 256 threads). Wave w reduces batch w's
// 128 block partials (blocks [w*128, w*128+128)); thread 0 assembles in f64.
// ---------------------------------------------------------------------------
__global__ __launch_bounds__(256) void final_reduce(
        const float* __restrict__ partials, float* __restrict__ out) {
    __shared__ float sb[NACC][4];
    int w = threadIdx.x >> 6, lane = threadIdx.x & 63;
#pragma unroll
    for (int k = 0; k < NACC; ++k) {
        const float* p = partials + k * NBLK + w * 128;
        float v = p[lane] + p[lane + 64];
#pragma unroll
        for (int off = 32; off; off >>= 1) v += __shfl_down(v, off, 64);
        if (lane == 0) sb[k][w] = v;
    }
    __syncthreads();
    if (threadIdx.x == 0) {
        double S[NACC];
#pragma unroll
        for (int k = 0; k < NACC; ++k)
            S[k] = (double)sb[k][0] + sb[k][1] + sb[k][2] + sb[k][3];
        const double W[3] = {0.3, 3.0, 0.3};
        double focal = -S[0] / (double)NVOX;
        double dice = 0.0;
        for (int c = 0; c < 3; ++c)
            dice += W[c] * (1.0 - (2.0 * S[1 + c] + 1.0) /
                                  (S[4 + c] + S[7 + c] + 1.0));
        double lfd = focal + dice / 3.6;
        double lsk = 1.0 - (S[10] + 1.0) / (S[11] + 1.0);
        double lb = 0.0;
        for (int bb = 0; bb < 4; ++bb) {
            double gs = sb[8][bb];
            double ps = sb[12][bb];
            double tm = sb[13][bb];
            double per;
            if (gs == 0.0)               per = ps / (double)VOXB;
            else if (gs == (double)VOXB) per = 1.0 - ps / (double)VOXB;
            else                         per = tm / (double)VOXB;
            lb += per;
        }
        lb *= 0.25;
        double total = 0.3 * lfd + 0.3 * lsk + 0.2 * lb;
        out[0] = (float)total;
        out[1] = (float)lfd;
        out[2] = (float)lsk;
        out[3] = (float)lb;
    }
}

// ---------------------------------------------------------------------------
extern "C" void kernel_launch(void* const* d_in, const int* in_sizes, int n_in,
                              void* d_out, int out_size, void* d_ws, size_t ws_size,
                              hipStream_t stream) {
    const float* logits  = (const float*)d_in[0];
    const int*   targets = (const int*)d_in[1];
    const int*   skel    = (const int*)d_in[2];
    unsigned int* d2wh   = (unsigned int*)d_ws;            // NVOX uints (4 MB)
    float* partials      = (float*)(d2wh + NVOX);          // NACC*NBLK floats
    float* out = (float*)d_out;

    edt_wh<<<NBLK, 512, 0, stream>>>(targets, d2wh);
    edt_d_reduce<<<NBLK, 512, 0, stream>>>(logits, targets, skel, d2wh,
                                           partials);
    final_reduce<<<1, 256, 0, stream>>>(partials, out);
}